// Round 5
// baseline (3771.351 us; speedup 1.0000x reference)
//
#include <hip/hip_runtime.h>
#include <math.h>

#define NDOF 4
#define NB   512
#define NT   64
#define ND   256
#define NS   1024           // NDOF*ND

// Grid decomposition (FIXED r4 bug: grid MUST be 128 to match this mapping):
// 128 blocks = 4 rt (128-row batch tiles, covers NB=512) x 32 nt (128 n'-cols).
#define NRT  4
#define GRID (NRT * 32)

typedef __attribute__((ext_vector_type(8))) __bf16 bf16x8;
typedef __attribute__((ext_vector_type(4))) float  f32x4;

__device__ __forceinline__ void gll16(const void* g, void* l) {
    __builtin_amdgcn_global_load_lds(
        (const __attribute__((address_space(1))) unsigned int*)g,
        (__attribute__((address_space(3))) unsigned int*)l, 16, 0, 0);
}

__device__ __forceinline__ float sig_(float x) { return 1.0f / (1.0f + __expf(-x)); }
__device__ __forceinline__ float tanh_(float x) {
    float e = __expf(-2.0f * fabsf(x));
    float t = (1.0f - e) / (1.0f + e);
    return copysignf(t, x);
}

// -------- device-scope group barrier (32 blocks sharing one rt) --------
// Agent-scope RELEASE/ACQUIRE atomics provide the cross-XCD L2 writeback /
// invalidate; explicit __threadfence() is redundant belt-and-suspenders.
struct __align__(64) Bar { unsigned cnt; unsigned gen; unsigned pad[14]; };

__device__ __forceinline__ void bar_sync(Bar* b, unsigned n) {
    __syncthreads();   // all waves' stores + gll16 drained (vmcnt 0)
    if (threadIdx.x == 0) {
        __threadfence();
        unsigned g = __hip_atomic_load(&b->gen, __ATOMIC_RELAXED, __HIP_MEMORY_SCOPE_AGENT);
        unsigned prev = __hip_atomic_fetch_add(&b->cnt, 1u, __ATOMIC_ACQ_REL, __HIP_MEMORY_SCOPE_AGENT);
        if (prev == n - 1u) {
            __hip_atomic_store(&b->cnt, 0u, __ATOMIC_RELAXED, __HIP_MEMORY_SCOPE_AGENT);
            __hip_atomic_store(&b->gen, g + 1u, __ATOMIC_RELEASE, __HIP_MEMORY_SCOPE_AGENT);
        } else {
            unsigned spins = 0;
            while (__hip_atomic_load(&b->gen, __ATOMIC_ACQUIRE, __HIP_MEMORY_SCOPE_AGENT) == g) {
                __builtin_amdgcn_s_sleep(8);
                if (++spins > (1u << 16)) break;   // failsafe: never hang the harness
            }
        }
        __threadfence();
    }
    __syncthreads();
}

struct Params {
    const __bf16* xbf;
    const __bf16* wT1;
    const __bf16* wT2;
    const float *b1u, *b1f, *b1o, *b1c;
    const float *b2u, *b2f, *b2o, *b2c;
    __bf16* hA;
    __bf16* hB;
    float*  out;
    Bar*    bars;
};

// ---- staging helpers (gll16 LDS dest is lane-linear by construction) ----
__device__ __forceinline__ void prefetchB(bf16x8* smem, const __bf16* wrow, int tid) {
    const int row = tid & 127, kgb = (tid >> 7) & 1;
    #pragma unroll
    for (int i = 0; i < 4; ++i) {
        const int kg = kgb + 2 * i;
        gll16(wrow + kg * 8, &smem[2048 + kg * 128 + row]);
    }
}
__device__ __forceinline__ void prefetchAx(bf16x8* smem, const __bf16* axbase, int tid) {
    const int row = tid & 127, kgb = (tid >> 7) & 1;
    #pragma unroll
    for (int i = 0; i < 4; ++i) {
        const int kg = kgb + 2 * i;
        gll16(axbase + (size_t)row * ND + kg * 8, &smem[kg * 128 + row]);
    }
}

// ---- core GEMM: C[128 x 128'] over K = NIT*64, double-buffered LDS ----
template<int NIT, int XIT, bool SKIP_B0, bool SKIP_A0>
__device__ __forceinline__ void gemm_phase(bf16x8* smem,
    const __bf16* __restrict__ axbase,   // x rows (stride ND), iters < XIT
    const __bf16* __restrict__ ahbase,   // h rows (stride NS), iters >= XIT
    const __bf16* __restrict__ wrow,     // per-thread weight row (wT + np*K)
    f32x4 (&acc)[4][4], int tid, int lane, int wr, int ws)
{
    const int row = tid & 127;
    const int kgb = (tid >> 7) & 1;

    auto stageB = [&](int it, int pb) {
        const int k0 = it * 64;
        #pragma unroll
        for (int i = 0; i < 4; ++i) {
            const int kg = kgb + 2 * i;
            gll16(wrow + k0 + kg * 8, &smem[2048 + pb * 1024 + kg * 128 + row]);
        }
    };
    auto stageA = [&](int it, int pb) {
        const int k0 = it * 64;
        const __bf16* ab;
        if (XIT > 0 && it < XIT) ab = axbase + (size_t)row * ND + k0;
        else                     ab = ahbase + (size_t)row * NS + (k0 - XIT * 64);
        #pragma unroll
        for (int i = 0; i < 4; ++i) {
            const int kg = kgb + 2 * i;
            gll16(ab + kg * 8, &smem[pb * 1024 + kg * 128 + row]);
        }
    };

    if (!SKIP_B0) stageB(0, 0);
    if (!SKIP_A0) stageA(0, 0);
    __syncthreads();
    int pb = 0;
    for (int it = 0; it < NIT; ++it) {
        if (it + 1 < NIT) { stageB(it + 1, pb ^ 1); stageA(it + 1, pb ^ 1); }
        #pragma unroll
        for (int sub = 0; sub < 2; ++sub) {
            const int kq = sub * 4 + (lane >> 4);
            bf16x8 a[4], b[4];
            #pragma unroll
            for (int mI = 0; mI < 4; ++mI)
                a[mI] = smem[pb * 1024 + kq * 128 + wr + mI * 16 + (lane & 15)];
            #pragma unroll
            for (int g = 0; g < 4; ++g)
                b[g] = smem[2048 + pb * 1024 + kq * 128 + g * 32 + ws * 16 + (lane & 15)];
            #pragma unroll
            for (int mI = 0; mI < 4; ++mI)
                #pragma unroll
                for (int g = 0; g < 4; ++g)
                    acc[mI][g] = __builtin_amdgcn_mfma_f32_16x16x32_bf16(a[mI], b[g], acc[mI][g], 0, 0, 0);
        }
        __syncthreads();
        pb ^= 1;
    }
}

// ---- in-lane LSTM epilogue (gate-major: gates live in acc[mI][0..3]) ----
template<bool LAST>
__device__ __forceinline__ void epilogue(const f32x4 (&acc)[4][4], float (&m_reg)[16],
    float bu, float bf_, float bo, float bc,
    __bf16* __restrict__ hout, float* __restrict__ out,
    int rbase, int scol, int dof, int colL)
{
    #pragma unroll
    for (int mI = 0; mI < 4; ++mI) {
        #pragma unroll
        for (int r = 0; r < 4; ++r) {
            const int row = rbase + mI * 16 + r;   // batch row in [0, 512)
            const float gu = sig_(acc[mI][0][r] + bu);
            const float gf = sig_(acc[mI][1][r] + bf_);
            const float go = sig_(acc[mI][2][r] + bo);
            const float gc = tanh_(acc[mI][3][r] + bc);
            float& m = m_reg[mI * 4 + r];
            m = gf * m + gu * gc;
            const float hv = tanh_(go * m);
            hout[(size_t)row * NS + scol] = (__bf16)hv;
            if (LAST) {
                const size_t oi = ((size_t)dof * NB + row) * ND + colL;
                out[oi] = hv;
                out[(size_t)NDOF * NB * ND + oi] = m;
            }
        }
    }
}

// 128 blocks x 256 threads, 64 KB LDS: 1 block/CU, all co-resident (2x CU
// margin) -> group spin barriers are deadlock-free.
__global__ __launch_bounds__(256)
void lstm_persistent(Params p)
{
    __shared__ bf16x8 smem[4096];   // 64 KB: A dbuf [0,2048), B dbuf [2048,4096)

    const int tid  = threadIdx.x;
    const int lane = tid & 63;
    const int wv   = tid >> 6;
    const int wr   = (wv >> 1) * 64;     // wave row-half
    const int ws   = wv & 1;             // wave col-strip (16 cols per gate)
    const int nt   = blockIdx.x & 31;    // nt%8 = XCD -> weight panel L2-resident
    const int rt   = blockIdx.x >> 5;    // [0, NRT) -- grid MUST be 128
    const int r0   = rt * 128;
    const int dof  = nt >> 3;
    const int c0   = (nt & 7) * 32;

    const int colL = c0 + ws * 16 + (lane & 15);   // col within dof [0,256)
    const int scol = dof * ND + colL;              // col in state row [0,1024)
    const int rbase = r0 + wr + (lane >> 4) * 4;

    // per-thread weight row (n' = dof*1024 + g*256 + col, k-contiguous)
    const int rowT = tid & 127;
    const int npT  = dof * 1024 + (rowT >> 5) * 256 + c0 + (rowT & 31);
    const __bf16* wrow1 = p.wT1 + (size_t)npT * 512;
    const __bf16* wrow2 = p.wT2 + (size_t)npT * 1024;

    const float b1u = p.b1u[scol], b1f = p.b1f[scol], b1o = p.b1o[scol], b1c = p.b1c[scol];
    const float b2u = p.b2u[scol], b2f = p.b2f[scol], b2o = p.b2o[scol], b2c = p.b2c[scol];

    float m_reg[16];
    #pragma unroll
    for (int i = 0; i < 16; ++i) m_reg[i] = 0.f;

    Bar* barA = &p.bars[rt * 2 + 0];
    Bar* barB = &p.bars[rt * 2 + 1];

    // preload step-0 phase-1 tile 0 (B weights + A x-part; it0 is x-only, XIT=4)
    prefetchB(smem, wrow1, tid);
    prefetchAx(smem, p.xbf + ((size_t)(dof * NT) * NB + r0) * ND, tid);

    for (int t = 0; t < NT; ++t) {
        // ---------- phase 1: per-dof cell, K=512 = [x_t | h_own] ----------
        f32x4 acc[4][4];
        #pragma unroll
        for (int mI = 0; mI < 4; ++mI)
            #pragma unroll
            for (int g = 0; g < 4; ++g) acc[mI][g] = (f32x4){0.f, 0.f, 0.f, 0.f};

        const __bf16* ax = p.xbf + ((size_t)(dof * NT + t) * NB + r0) * ND;
        gemm_phase<8, 4, true, true>(smem, ax, p.hA + (size_t)r0 * NS + dof * ND,
                                     wrow1, acc, tid, lane, wr, ws);
        prefetchB(smem, wrow2, tid);   // phase-2 weights tile0 -> hides under barrier
        epilogue<false>(acc, m_reg, b1u, b1f, b1o, b1c, p.hB, nullptr, rbase, scol, dof, colL);
        bar_sync(barA, 32);

        // ---------- phase 2: grid coupling, K=1024 = full h row ----------
        #pragma unroll
        for (int mI = 0; mI < 4; ++mI)
            #pragma unroll
            for (int g = 0; g < 4; ++g) acc[mI][g] = (f32x4){0.f, 0.f, 0.f, 0.f};

        gemm_phase<16, 0, true, false>(smem, nullptr, p.hB + (size_t)r0 * NS,
                                       wrow2, acc, tid, lane, wr, ws);
        if (t + 1 < NT) {
            prefetchB(smem, wrow1, tid);   // next step's phase-1 tile 0
            prefetchAx(smem, p.xbf + ((size_t)(dof * NT + t + 1) * NB + r0) * ND, tid);
            epilogue<false>(acc, m_reg, b2u, b2f, b2o, b2c, p.hA, nullptr, rbase, scol, dof, colL);
            bar_sync(barB, 32);
        } else {
            epilogue<true>(acc, m_reg, b2u, b2f, b2o, b2c, p.hA, p.out, rbase, scol, dof, colL);
        }
    }
}

// ---- one-time prep: x[d][b][t][:] fp32 -> xbf[d][t][b][:] bf16 ----
__global__ __launch_bounds__(256)
void convert_x(const float* __restrict__ x, __bf16* __restrict__ xbf)
{
    const int id  = blockIdx.x * 256 + threadIdx.x;   // 4,194,304 total
    const int d0  = (id & 31) * 8;
    const int t   = (id >> 5) & 63;
    const int b   = (id >> 11) & 511;
    const int dof = id >> 20;
    const float* s = x + (((size_t)dof * NB + b) * NT + t) * ND + d0;
    const float4 v0 = *(const float4*)s;
    const float4 v1 = *(const float4*)(s + 4);
    bf16x8 o;
    o[0] = (__bf16)v0.x; o[1] = (__bf16)v0.y; o[2] = (__bf16)v0.z; o[3] = (__bf16)v0.w;
    o[4] = (__bf16)v1.x; o[5] = (__bf16)v1.y; o[6] = (__bf16)v1.z; o[7] = (__bf16)v1.w;
    *(bf16x8*)(xbf + (((size_t)dof * NT + t) * NB + b) * ND + d0) = o;
}

// ---- one-time prep: weights -> bf16 wT[n'][k], n' = dof*1024 + g*256 + col ----
__global__ __launch_bounds__(256)
void transpose_weights(const float* __restrict__ wu, const float* __restrict__ wf,
                       const float* __restrict__ wo, const float* __restrict__ wcp,
                       const float* __restrict__ gwu, const float* __restrict__ gwf,
                       const float* __restrict__ gwo, const float* __restrict__ gwc,
                       __bf16* __restrict__ wT1, __bf16* __restrict__ wT2)
{
    int id = blockIdx.x * 256 + threadIdx.x;
    const int C1 = 4096 * 64;
    int K, np, kc;
    const float *s0, *s1, *s2, *s3;
    __bf16* dst;
    if (id < C1) { K = 512;  np = id & 4095; kc = id >> 12; dst = wT1; s0 = wu;  s1 = wf;  s2 = wo;  s3 = wcp; }
    else { id -= C1; K = 1024; np = id & 4095; kc = id >> 12; dst = wT2; s0 = gwu; s1 = gwf; s2 = gwo; s3 = gwc; }
    const int dof = np >> 10, q = np & 1023, g = q >> 8, col = q & 255;
    const float* w = ((g == 0) ? s0 : (g == 1) ? s1 : (g == 2) ? s2 : s3)
                     + ((size_t)dof * K + kc * 8) * ND + col;
    bf16x8 o;
    #pragma unroll
    for (int j = 0; j < 8; ++j) o[j] = (__bf16)w[j * ND];
    *(bf16x8*)(dst + (size_t)np * K + kc * 8) = o;
}

extern "C" void kernel_launch(void* const* d_in, const int* in_sizes, int n_in,
                              void* d_out, int out_size, void* d_ws, size_t ws_size,
                              hipStream_t stream)
{
    const float* x   = (const float*)d_in[0];
    const float* wu  = (const float*)d_in[1];
    const float* wf  = (const float*)d_in[2];
    const float* wo  = (const float*)d_in[3];
    const float* wc  = (const float*)d_in[4];

    char* ws = (char*)d_ws;
    __bf16* wT1 = (__bf16*)ws;                        //  4 MB  [4096][512]
    __bf16* wT2 = (__bf16*)(ws + (4u  << 20));        //  8 MB  [4096][1024]
    __bf16* xbf = (__bf16*)(ws + (12u << 20));        // 64 MB  [4][64][512][256]
    __bf16* hA  = (__bf16*)(ws + (76u << 20));        //  1 MB
    __bf16* hB  = (__bf16*)(ws + (77u << 20));        //  1 MB
    Bar*    bars = (Bar*)  (ws + (78u << 20));        //  1 KB (16 x 64B)

    convert_x<<<16384, 256, 0, stream>>>(x, xbf);
    transpose_weights<<<3072, 256, 0, stream>>>(
        wu, wf, wo, wc,
        (const float*)d_in[9], (const float*)d_in[10],
        (const float*)d_in[11], (const float*)d_in[12], wT1, wT2);
    // zero hA + hB + barrier state each call (deterministic across replays)
    hipMemsetAsync(ws + (76u << 20), 0, (2u << 20) + 4096, stream);

    Params p;
    p.xbf = xbf; p.wT1 = wT1; p.wT2 = wT2;
    p.b1u = (const float*)d_in[5];  p.b1f = (const float*)d_in[6];
    p.b1o = (const float*)d_in[7];  p.b1c = (const float*)d_in[8];
    p.b2u = (const float*)d_in[13]; p.b2f = (const float*)d_in[14];
    p.b2o = (const float*)d_in[15]; p.b2c = (const float*)d_in[16];
    p.hA = hA; p.hB = hB; p.out = (float*)d_out; p.bars = bars;

    lstm_persistent<<<dim3(GRID), dim3(256), 0, stream>>>(p);
}

// Round 6
// 2878.815 us; speedup vs baseline: 1.3100x; 1.3100x over previous
//
#include <hip/hip_runtime.h>
#include <math.h>

#define NDOF 4
#define NB   512
#define NT   64
#define ND   256
#define NS   1024           // NDOF*ND

// 128 blocks = 4 rt (128-row batch tiles) x 32 nt (128 n'-cols).
#define NRT  4
#define GRID (NRT * 32)

typedef __attribute__((ext_vector_type(8))) __bf16 bf16x8;
typedef __attribute__((ext_vector_type(4))) float  f32x4;

__device__ __forceinline__ void gll16(const void* g, void* l) {
    __builtin_amdgcn_global_load_lds(
        (const __attribute__((address_space(1))) unsigned int*)g,
        (__attribute__((address_space(3))) unsigned int*)l, 16, 0, 0);
}

__device__ __forceinline__ float sig_(float x) { return 1.0f / (1.0f + __expf(-x)); }
__device__ __forceinline__ float tanh_(float x) {
    float e = __expf(-2.0f * fabsf(x));
    float t = (1.0f - e) / (1.0f + e);
    return copysignf(t, x);
}

// device-scope (cross-XCD coherent) h store: sc0 sc1 = bypass L1+L2,
// write-through to MALL. No cache maintenance needed anywhere.
__device__ __forceinline__ void store_h_dev(__bf16* p, float hv) {
    __bf16 hb = (__bf16)hv;
    unsigned v = (unsigned)__builtin_bit_cast(unsigned short, hb);
    asm volatile("global_store_short %0, %1, off sc0 sc1" :: "v"(p), "v"(v) : "memory");
}

// -------- group barrier (32 blocks sharing one rt), scope-precise --------
// RELAXED agent atomics only (no buffer_inv / buffer_wbl2 L2 walks!).
// cnt is monotonic (no reset); expected generation e is derived locally, so
// correctness never depends on a cached flag read. Poll uses fetch_add(0):
// an RMW always round-trips to the MALL coherence point.
struct __align__(64) Bar { unsigned cnt; unsigned gen; unsigned pad[14]; };

__device__ __forceinline__ void bar_sync(Bar* b, unsigned n, unsigned e) {
    __syncthreads();   // drains vmcnt: all sc1 h-stores + gll16 complete
    if (threadIdx.x == 0) {
        unsigned prev = __hip_atomic_fetch_add(&b->cnt, 1u, __ATOMIC_RELAXED, __HIP_MEMORY_SCOPE_AGENT);
        if (prev == e * n - 1u) {
            __hip_atomic_fetch_add(&b->gen, 1u, __ATOMIC_RELAXED, __HIP_MEMORY_SCOPE_AGENT);  // -> e
        } else {
            unsigned spins = 0;
            while (__hip_atomic_fetch_add(&b->gen, 0u, __ATOMIC_RELAXED, __HIP_MEMORY_SCOPE_AGENT) < e) {
                __builtin_amdgcn_s_sleep(2);
                if (++spins > (1u << 17)) break;   // failsafe: fail loud, never hang
            }
        }
    }
    __syncthreads();
    asm volatile("" ::: "memory");
}

struct Params {
    const __bf16* xbf;
    const __bf16* wT1;
    const __bf16* wT2;
    const float *b1u, *b1f, *b1o, *b1c;
    const float *b2u, *b2f, *b2o, *b2c;
    __bf16* hA;
    __bf16* hB;
    float*  out;
    Bar*    bars;
};

// ---- cached prefetch helpers (read-only data: weights, x) ----
__device__ __forceinline__ void prefetchB(bf16x8* smem, const __bf16* wrow, int tid) {
    const int row = tid & 127, kgb = (tid >> 7) & 1;
    #pragma unroll
    for (int i = 0; i < 4; ++i) {
        const int kg = kgb + 2 * i;
        gll16(wrow + kg * 8, &smem[2048 + kg * 128 + row]);
    }
}
__device__ __forceinline__ void prefetchAx(bf16x8* smem, const __bf16* axbase, int tid) {
    const int row = tid & 127, kgb = (tid >> 7) & 1;
    #pragma unroll
    for (int i = 0; i < 4; ++i) {
        const int kg = kgb + 2 * i;
        gll16(axbase + (size_t)row * ND + kg * 8, &smem[kg * 128 + row]);
    }
}

// ---- core GEMM: C[128 x 128'] over K = NIT*64, double-buffered LDS ----
// A rows from x: cached gll16 (iters < XIT). A rows from h: device-scope
// asm loads (sc0 sc1) reg-staged, committed to LDS after compute (T14 split).
// PRE_AB0: tile 0 (A and B) already prefetched into buffer 0.
template<int NIT, int XIT, bool PRE_AB0>
__device__ __forceinline__ void gemm_phase(bf16x8* smem,
    const __bf16* __restrict__ axbase,
    const __bf16* __restrict__ ahbase,
    const __bf16* __restrict__ wrow,
    f32x4 (&acc)[4][4], int tid, int lane, int wr, int ws)
{
    const int row = tid & 127;
    const int kgb = (tid >> 7) & 1;
    bf16x8 areg0, areg1, areg2, areg3;   // named -> static reg alloc (no scratch)

    auto stageB = [&](int it, int pb) {
        const int k0 = it * 64;
        #pragma unroll
        for (int i = 0; i < 4; ++i) {
            const int kg = kgb + 2 * i;
            gll16(wrow + k0 + kg * 8, &smem[2048 + pb * 1024 + kg * 128 + row]);
        }
    };
    auto stageAx = [&](int it, int pb) {
        const int k0 = it * 64;
        #pragma unroll
        for (int i = 0; i < 4; ++i) {
            const int kg = kgb + 2 * i;
            gll16(axbase + (size_t)row * ND + k0 + kg * 8,
                  &smem[pb * 1024 + kg * 128 + row]);
        }
    };
    auto issueAh = [&](int it) {
        const __bf16* ab = ahbase + (size_t)row * NS + (size_t)(it - XIT) * 64;
        asm volatile("global_load_dwordx4 %0, %1, off sc0 sc1" : "=v"(areg0) : "v"(ab + (kgb + 0) * 8) : "memory");
        asm volatile("global_load_dwordx4 %0, %1, off sc0 sc1" : "=v"(areg1) : "v"(ab + (kgb + 2) * 8) : "memory");
        asm volatile("global_load_dwordx4 %0, %1, off sc0 sc1" : "=v"(areg2) : "v"(ab + (kgb + 4) * 8) : "memory");
        asm volatile("global_load_dwordx4 %0, %1, off sc0 sc1" : "=v"(areg3) : "v"(ab + (kgb + 6) * 8) : "memory");
    };
    auto commitAh = [&](int pb) {
        asm volatile("s_waitcnt vmcnt(0)" ::: "memory");
        smem[pb * 1024 + (kgb + 0) * 128 + row] = areg0;
        smem[pb * 1024 + (kgb + 2) * 128 + row] = areg1;
        smem[pb * 1024 + (kgb + 4) * 128 + row] = areg2;
        smem[pb * 1024 + (kgb + 6) * 128 + row] = areg3;
    };

    if (!PRE_AB0) {        // phase 2: B tile0 was prefetched; A tile0 from h
        issueAh(0);
        commitAh(0);
    }
    __syncthreads();

    int pb = 0;
    for (int it = 0; it < NIT; ++it) {
        const bool nx = (it + 1 < NIT);
        if (nx) {
            stageB(it + 1, pb ^ 1);
            if (it + 1 < XIT) stageAx(it + 1, pb ^ 1);
            else              issueAh(it + 1);
        }
        #pragma unroll
        for (int sub = 0; sub < 2; ++sub) {
            const int kq = sub * 4 + (lane >> 4);
            bf16x8 a[4], b[4];
            #pragma unroll
            for (int mI = 0; mI < 4; ++mI)
                a[mI] = smem[pb * 1024 + kq * 128 + wr + mI * 16 + (lane & 15)];
            #pragma unroll
            for (int g = 0; g < 4; ++g)
                b[g] = smem[2048 + pb * 1024 + kq * 128 + g * 32 + ws * 16 + (lane & 15)];
            #pragma unroll
            for (int mI = 0; mI < 4; ++mI)
                #pragma unroll
                for (int g = 0; g < 4; ++g)
                    acc[mI][g] = __builtin_amdgcn_mfma_f32_16x16x32_bf16(a[mI], b[g], acc[mI][g], 0, 0, 0);
        }
        if (nx && it + 1 >= XIT) commitAh(pb ^ 1);
        __syncthreads();
        pb ^= 1;
    }
}

// ---- in-lane LSTM epilogue (gate-major: gates live in acc[mI][0..3]) ----
template<bool LAST>
__device__ __forceinline__ void epilogue(const f32x4 (&acc)[4][4], float (&m_reg)[16],
    float bu, float bf_, float bo, float bc,
    __bf16* __restrict__ hout, float* __restrict__ out,
    int rbase, int scol, int dof, int colL)
{
    #pragma unroll
    for (int mI = 0; mI < 4; ++mI) {
        #pragma unroll
        for (int r = 0; r < 4; ++r) {
            const int row = rbase + mI * 16 + r;   // batch row in [0, 512)
            const float gu = sig_(acc[mI][0][r] + bu);
            const float gf = sig_(acc[mI][1][r] + bf_);
            const float go = sig_(acc[mI][2][r] + bo);
            const float gc = tanh_(acc[mI][3][r] + bc);
            float& m = m_reg[mI * 4 + r];
            m = gf * m + gu * gc;
            const float hv = tanh_(go * m);
            if (LAST) {
                const size_t oi = ((size_t)dof * NB + row) * ND + colL;
                out[oi] = hv;
                out[(size_t)NDOF * NB * ND + oi] = m;
            } else {
                store_h_dev(&hout[(size_t)row * NS + scol], hv);
            }
        }
    }
}

// 128 blocks x 256 threads, 64 KB LDS: 1 block/CU, all co-resident (2x CU
// margin) -> group spin barriers are deadlock-free.
// launch_bounds(...,1): allow >256 VGPR (1 wave/SIMD is the design point).
__global__ __launch_bounds__(256, 1)
void lstm_persistent(Params p)
{
    __shared__ bf16x8 smem[4096];   // 64 KB: A dbuf [0,2048), B dbuf [2048,4096)

    const int tid  = threadIdx.x;
    const int lane = tid & 63;
    const int wv   = tid >> 6;
    const int wr   = (wv >> 1) * 64;     // wave row-half
    const int ws   = wv & 1;             // wave col-strip (16 cols per gate)
    const int nt   = blockIdx.x & 31;    // nt%8 spreads a group across XCDs (perf only)
    const int rt   = blockIdx.x >> 5;    // [0, NRT)
    const int r0   = rt * 128;
    const int dof  = nt >> 3;
    const int c0   = (nt & 7) * 32;

    const int colL = c0 + ws * 16 + (lane & 15);   // col within dof [0,256)
    const int scol = dof * ND + colL;              // col in state row [0,1024)
    const int rbase = r0 + wr + (lane >> 4) * 4;

    // per-thread weight row (n' = dof*1024 + g*256 + col, k-contiguous)
    const int rowT = tid & 127;
    const int npT  = dof * 1024 + (rowT >> 5) * 256 + c0 + (rowT & 31);
    const __bf16* wrow1 = p.wT1 + (size_t)npT * 512;
    const __bf16* wrow2 = p.wT2 + (size_t)npT * 1024;

    const float b1u = p.b1u[scol], b1f = p.b1f[scol], b1o = p.b1o[scol], b1c = p.b1c[scol];
    const float b2u = p.b2u[scol], b2f = p.b2f[scol], b2o = p.b2o[scol], b2c = p.b2c[scol];

    float m_reg[16];
    #pragma unroll
    for (int i = 0; i < 16; ++i) m_reg[i] = 0.f;

    Bar* barA = &p.bars[rt * 2 + 0];
    Bar* barB = &p.bars[rt * 2 + 1];

    // preload step-0 phase-1 tile 0 (B weights + A x-part; tile0 is x, XIT=4)
    prefetchB(smem, wrow1, tid);
    prefetchAx(smem, p.xbf + ((size_t)(dof * NT) * NB + r0) * ND, tid);

    for (int t = 0; t < NT; ++t) {
        // ---------- phase 1: per-dof cell, K=512 = [x_t | h_own] ----------
        f32x4 acc[4][4];
        #pragma unroll
        for (int mI = 0; mI < 4; ++mI)
            #pragma unroll
            for (int g = 0; g < 4; ++g) acc[mI][g] = (f32x4){0.f, 0.f, 0.f, 0.f};

        const __bf16* ax = p.xbf + ((size_t)(dof * NT + t) * NB + r0) * ND;
        gemm_phase<8, 4, true>(smem, ax, p.hA + (size_t)r0 * NS + dof * ND,
                               wrow1, acc, tid, lane, wr, ws);
        prefetchB(smem, wrow2, tid);   // phase-2 weights tile0 (cached, L2-hot)
        epilogue<false>(acc, m_reg, b1u, b1f, b1o, b1c, p.hB, nullptr, rbase, scol, dof, colL);
        bar_sync(barA, 32, (unsigned)(t + 1));

        // ---------- phase 2: grid coupling, K=1024 = full h row ----------
        #pragma unroll
        for (int mI = 0; mI < 4; ++mI)
            #pragma unroll
            for (int g = 0; g < 4; ++g) acc[mI][g] = (f32x4){0.f, 0.f, 0.f, 0.f};

        gemm_phase<16, 0, false>(smem, nullptr, p.hB + (size_t)r0 * NS,
                                 wrow2, acc, tid, lane, wr, ws);
        if (t + 1 < NT) {
            prefetchB(smem, wrow1, tid);   // next step's phase-1 tile 0
            prefetchAx(smem, p.xbf + ((size_t)(dof * NT + t + 1) * NB + r0) * ND, tid);
            epilogue<false>(acc, m_reg, b2u, b2f, b2o, b2c, p.hA, nullptr, rbase, scol, dof, colL);
            bar_sync(barB, 32, (unsigned)(t + 1));
        } else {
            epilogue<true>(acc, m_reg, b2u, b2f, b2o, b2c, p.hA, p.out, rbase, scol, dof, colL);
        }
    }
}

// ---- one-time prep: x[d][b][t][:] fp32 -> xbf[d][t][b][:] bf16 ----
__global__ __launch_bounds__(256)
void convert_x(const float* __restrict__ x, __bf16* __restrict__ xbf)
{
    const int id  = blockIdx.x * 256 + threadIdx.x;   // 4,194,304 total
    const int d0  = (id & 31) * 8;
    const int t   = (id >> 5) & 63;
    const int b   = (id >> 11) & 511;
    const int dof = id >> 20;
    const float* s = x + (((size_t)dof * NB + b) * NT + t) * ND + d0;
    const float4 v0 = *(const float4*)s;
    const float4 v1 = *(const float4*)(s + 4);
    bf16x8 o;
    o[0] = (__bf16)v0.x; o[1] = (__bf16)v0.y; o[2] = (__bf16)v0.z; o[3] = (__bf16)v0.w;
    o[4] = (__bf16)v1.x; o[5] = (__bf16)v1.y; o[6] = (__bf16)v1.z; o[7] = (__bf16)v1.w;
    *(bf16x8*)(xbf + (((size_t)dof * NT + t) * NB + b) * ND + d0) = o;
}

// ---- one-time prep: weights -> bf16 wT[n'][k], n' = dof*1024 + g*256 + col ----
__global__ __launch_bounds__(256)
void transpose_weights(const float* __restrict__ wu, const float* __restrict__ wf,
                       const float* __restrict__ wo, const float* __restrict__ wcp,
                       const float* __restrict__ gwu, const float* __restrict__ gwf,
                       const float* __restrict__ gwo, const float* __restrict__ gwc,
                       __bf16* __restrict__ wT1, __bf16* __restrict__ wT2)
{
    int id = blockIdx.x * 256 + threadIdx.x;
    const int C1 = 4096 * 64;
    int K, np, kc;
    const float *s0, *s1, *s2, *s3;
    __bf16* dst;
    if (id < C1) { K = 512;  np = id & 4095; kc = id >> 12; dst = wT1; s0 = wu;  s1 = wf;  s2 = wo;  s3 = wcp; }
    else { id -= C1; K = 1024; np = id & 4095; kc = id >> 12; dst = wT2; s0 = gwu; s1 = gwf; s2 = gwo; s3 = gwc; }
    const int dof = np >> 10, q = np & 1023, g = q >> 8, col = q & 255;
    const float* w = ((g == 0) ? s0 : (g == 1) ? s1 : (g == 2) ? s2 : s3)
                     + ((size_t)dof * K + kc * 8) * ND + col;
    bf16x8 o;
    #pragma unroll
    for (int j = 0; j < 8; ++j) o[j] = (__bf16)w[j * ND];
    *(bf16x8*)(dst + (size_t)np * K + kc * 8) = o;
}

extern "C" void kernel_launch(void* const* d_in, const int* in_sizes, int n_in,
                              void* d_out, int out_size, void* d_ws, size_t ws_size,
                              hipStream_t stream)
{
    const float* x   = (const float*)d_in[0];
    const float* wu  = (const float*)d_in[1];
    const float* wf  = (const float*)d_in[2];
    const float* wo  = (const float*)d_in[3];
    const float* wc  = (const float*)d_in[4];

    char* ws = (char*)d_ws;
    __bf16* wT1 = (__bf16*)ws;                        //  4 MB  [4096][512]
    __bf16* wT2 = (__bf16*)(ws + (4u  << 20));        //  8 MB  [4096][1024]
    __bf16* xbf = (__bf16*)(ws + (12u << 20));        // 64 MB  [4][64][512][256]
    __bf16* hA  = (__bf16*)(ws + (76u << 20));        //  1 MB
    __bf16* hB  = (__bf16*)(ws + (77u << 20));        //  1 MB
    Bar*    bars = (Bar*)  (ws + (78u << 20));        //  1 KB (16 x 64B)

    convert_x<<<16384, 256, 0, stream>>>(x, xbf);
    transpose_weights<<<3072, 256, 0, stream>>>(
        wu, wf, wo, wc,
        (const float*)d_in[9], (const float*)d_in[10],
        (const float*)d_in[11], (const float*)d_in[12], wT1, wT2);
    // zero hA + hB + barrier state each call (deterministic across replays)
    hipMemsetAsync(ws + (76u << 20), 0, (2u << 20) + 4096, stream);

    Params p;
    p.xbf = xbf; p.wT1 = wT1; p.wT2 = wT2;
    p.b1u = (const float*)d_in[5];  p.b1f = (const float*)d_in[6];
    p.b1o = (const float*)d_in[7];  p.b1c = (const float*)d_in[8];
    p.b2u = (const float*)d_in[13]; p.b2f = (const float*)d_in[14];
    p.b2o = (const float*)d_in[15]; p.b2c = (const float*)d_in[16];
    p.hA = hA; p.hB = hB; p.out = (float*)d_out; p.bars = bars;

    lstm_persistent<<<dim3(GRID), dim3(256), 0, stream>>>(p);
}